// Round 17
// baseline (232.197 us; speedup 1.0000x reference)
//
#include <hip/hip_runtime.h>

typedef unsigned int u32;
typedef unsigned short u16;
typedef __bf16 bf16x8 __attribute__((ext_vector_type(8)));
typedef float f32x4 __attribute__((ext_vector_type(4)));
typedef u16 u16x8 __attribute__((ext_vector_type(8)));
typedef u16 u16x4 __attribute__((ext_vector_type(4)));

#define DEVI static __device__ __forceinline__

DEVI u16 f2bf(float f) {
  union { float f; u32 u; } v; v.f = f;
  return (u16)((v.u + 0x7fffu + ((v.u >> 16) & 1u)) >> 16);
}

DEVI u32 cvtpk(float a, float b) {  // lo=bf16(a), hi=bf16(b)
  u32 r;
  asm("v_cvt_pk_bf16_f32 %0, %1, %2" : "=v"(r) : "v"(a), "v"(b));
  return r;
}

// Problem constants: B=32, T=512, C=1024, H=16, D=64
constexpr long QS_ = 16777216;            // B*H*T*D elements (one of Q/K/V)
constexpr long XB_O    = 0;               // [16384][1024] bf16 x
constexpr long WQKV_O  = 16777216;        // [3072][1024]  bf16 fused W^T (q|k|v)
constexpr long Q_O     = 19922944;        // Q,K,V each [B*H][T][D] bf16 (Q pre-scaled!)
constexpr long CTX_O   = 70254592;        // [16384][1024] bf16 attention output
constexpr long WPROJ_O = 87031808;        // [1024][1024]  bf16 w_proj^T

// (1/sqrt(C)) * log2(e): folded into Q at GEMM1 epilogue so attn does exp2(s) directly.
#define SCL_Q 0.045084220027780106f

// ------------- fused prep: 64x64 LDS-transpose W packs (coalesced both sides) + x cast -------------
__global__ __launch_bounds__(256) void k_prep_all(const float* __restrict__ x,
                                                  const float* __restrict__ wq,
                                                  const float* __restrict__ wk,
                                                  const float* __restrict__ wv,
                                                  const float* __restrict__ wp,
                                                  u16* __restrict__ ws) {
  __shared__ float tile[64][65];
  const int b = blockIdx.x;
  const int tid = threadIdx.x;
  if (b < 1024) {
    const float* src;
    u16* dst;
    long srs;
    if (b < 768) {
      int sel = b >> 8, rest = b & 255, h = rest >> 4, kt = rest & 15;
      const float* W = (sel == 0) ? wq : ((sel == 1) ? wk : wv);
      src = W + (long)(h * 1024 + kt * 64) * 64;
      srs = 64;
      dst = ws + WQKV_O + (long)(sel * 1024 + h * 64) * 1024 + kt * 64;
    } else {
      int b3 = b - 768, ntile = b3 >> 4, kt = b3 & 15;
      src = wp + (long)(kt * 64) * 1024 + ntile * 64;
      srs = 1024;
      dst = ws + WPROJ_O + (long)(ntile * 64) * 1024 + kt * 64;
    }
    #pragma unroll
    for (int i = 0; i < 4; ++i) {
      int idx = i * 256 + tid, r = idx >> 4, c4 = idx & 15;
      float4 v = *(const float4*)(src + (long)r * srs + c4 * 4);
      tile[r][c4 * 4 + 0] = v.x; tile[r][c4 * 4 + 1] = v.y;
      tile[r][c4 * 4 + 2] = v.z; tile[r][c4 * 4 + 3] = v.w;
    }
    __syncthreads();
    #pragma unroll
    for (int i = 0; i < 2; ++i) {
      int idx = i * 256 + tid, dr = idx >> 3, c8 = idx & 7;
      u16x8 o8;
      #pragma unroll
      for (int j = 0; j < 8; ++j) o8[j] = f2bf(tile[c8 * 8 + j][dr]);
      *(u16x8*)(dst + (long)dr * 1024 + c8 * 8) = o8;
    }
  } else {
    long id = (long)(b - 1024) * 256 + tid;
    const float4* p = (const float4*)(x + id * 8);
    float4 a = p[0], c = p[1];
    u16x8 r;
    r[0]=f2bf(a.x); r[1]=f2bf(a.y); r[2]=f2bf(a.z); r[3]=f2bf(a.w);
    r[4]=f2bf(c.x); r[5]=f2bf(c.y); r[6]=f2bf(c.z); r[7]=f2bf(c.w);
    *(u16x8*)(ws + XB_O + id * 8) = r;
  }
}

DEVI void gload16(const u16* g, u16* l) {
  __builtin_amdgcn_global_load_lds((const __attribute__((address_space(1))) u32*)g,
                                   (__attribute__((address_space(3))) u32*)l, 16, 0, 0);
}

// ===================== 256x256 bf16 GEMM, 8 micro-phases, persistent PANELS =====================
// FROZEN (R15 state). Structural closure: acc(128 reg-equiv) + frags => ~236 regs/wave =>
// 1 block/CU hard bound; 128-tile @3 blocks/CU measured worse (R2: 763 TF vs 885 here).
template <int NN, int EPI, int PANELS>
__global__ __launch_bounds__(512, 2)
void k_gemm(const u16* __restrict__ A, const u16* __restrict__ Bt,
            u16* __restrict__ oq, float* __restrict__ of, const float* __restrict__ bias) {
  __shared__ u16 lds[2][4][8192];   // [buf][Alo,Ahi,Blo,Bhi]

  const int tid = threadIdx.x;
  const int lane = tid & 63;
  const int w = tid >> 6;           // 8 waves
  const int wm = w >> 2, wn = w & 3;
  const int lg = lane >> 4, lr = lane & 15;
  const int bht = 2 + (wn >> 1);    // this wave's B half-tile
  const int bn0 = (wn & 1) * 4;     // B subtile-row base within half-tile

  constexpr int NBG = NN / 256 / PANELS;   // bn groups per bm
  constexpr int NG = 16 * PANELS;          // total K-tiles across panels
  const int nwg = gridDim.x;
  const int swz = ((int)blockIdx.x & 7) * (nwg >> 3) + ((int)blockIdx.x >> 3);
  const int bm = swz / NBG, bng = swz % NBG;
  const long m0 = (long)bm * 256;

  int srcoff[2];
  #pragma unroll
  for (int r2 = 0; r2 < 2; ++r2) {
    int s = r2 * 8 + w;
    int mi = s >> 1, ks = s & 1;
    int rowl = mi * 16 + (lane >> 2);
    int colu = ks * 32 + (((lane & 3) * 8) ^ (((lane >> 5) & 1) * 16));
    srcoff[r2] = rowl * 1024 + colu;
  }
  const int fo = lr * 32 + ((lg * 8) ^ (((lr >> 3) & 1) * 16));

  const u16* At    = A  + m0 * 1024;
  const u16* Bbase = Bt + (long)bng * PANELS * 262144;   // 256 rows * 1024 per panel

  f32x4 acc[8][4] = {};
  bf16x8 aq[2][2][2];   // [set][mi2][ks] ping-pong A quarters
  bf16x8 bfr[4][2];     // persistent B fragments (all 4 nj)

#define STAGE(buf_, ht_, gbase_)                                               \
  { _Pragma("unroll") for (int r_ = 0; r_ < 2; ++r_)                           \
      gload16((gbase_) + srcoff[r_], &lds[buf_][ht_][r_ * 4096 + w * 512]); }

#define LDS_AQ(set_, buf_, q_)                                                 \
  { _Pragma("unroll") for (int i_ = 0; i_ < 2; ++i_)                           \
    _Pragma("unroll") for (int ks_ = 0; ks_ < 2; ++ks_)                        \
      aq[set_][i_][ks_] = *(const bf16x8*)&lds[buf_][wm][(((q_)*2 + i_) * 2 + ks_) * 512 + fo]; }

#define LDS_BF(buf_, lo_)                                                      \
  { _Pragma("unroll") for (int j_ = 0; j_ < 2; ++j_)                           \
    _Pragma("unroll") for (int ks_ = 0; ks_ < 2; ++ks_)                        \
      bfr[(lo_) + j_][ks_] = *(const bf16x8*)&lds[buf_][bht][((bn0 + (lo_) + j_) * 2 + ks_) * 512 + fo]; }

#define QUAD8(set_, q_, lo_)                                                   \
  { __builtin_amdgcn_s_setprio(1);                                             \
    _Pragma("unroll") for (int ks_ = 0; ks_ < 2; ++ks_)                        \
    _Pragma("unroll") for (int i_ = 0; i_ < 2; ++i_)                           \
    _Pragma("unroll") for (int j_ = 0; j_ < 2; ++j_)                           \
      acc[(q_)*2 + i_][(lo_) + j_] = __builtin_amdgcn_mfma_f32_16x16x32_bf16(  \
          aq[set_][i_][ks_], bfr[(lo_) + j_][ks_], acc[(q_)*2 + i_][(lo_) + j_], 0, 0, 0); \
    __builtin_amdgcn_s_setprio(0); }

#define BARF() { asm volatile("s_barrier" ::: "memory"); }

  auto epilogue = [&](int p) {
    const int n0 = (bng * PANELS + p) * 256;
    if constexpr (EPI == 0) {
      #pragma unroll
      for (int mi = 0; mi < 8; ++mi) {
        int grow = (int)m0 + wm * 128 + mi * 16 + lg * 4;
        int b = grow >> 9, t0 = grow & 511;
        #pragma unroll
        for (int ni = 0; ni < 4; ++ni) {
          int gcol = n0 + wn * 64 + ni * 16 + lr;
          int sel = gcol >> 10, h = (gcol >> 6) & 15, d = gcol & 63;
          float scl = (sel == 0) ? SCL_Q : 1.0f;   // fold softmax scale into Q
          u16* dst = oq + (long)sel * QS_ + (((long)(b * 16 + h) * 512 + t0) * 64 + d);
          #pragma unroll
          for (int r = 0; r < 4; ++r) dst[r * 64] = f2bf(acc[mi][ni][r] * scl);
        }
      }
    } else {
      float bv[4];
      #pragma unroll
      for (int ni = 0; ni < 4; ++ni) bv[ni] = bias[n0 + wn * 64 + ni * 16 + lr];
      #pragma unroll
      for (int mi = 0; mi < 8; ++mi) {
        int grow = (int)m0 + wm * 128 + mi * 16 + lg * 4;
        #pragma unroll
        for (int ni = 0; ni < 4; ++ni) {
          int gcol = n0 + wn * 64 + ni * 16 + lr;
          #pragma unroll
          for (int r = 0; r < 4; ++r)
            of[(long)(grow + r) * NN + gcol] = acc[mi][ni][r] + bv[ni];
        }
      }
    }
  };

  STAGE(0, 0, At);
  STAGE(0, 1, At + 131072);
  STAGE(0, 2, Bbase);
  STAGE(0, 3, Bbase + 131072);
  STAGE(1, 0, At + 64);
  STAGE(1, 1, At + 131072 + 64);
  STAGE(1, 2, Bbase + 64);
  STAGE(1, 3, Bbase + 131072 + 64);
  asm volatile("s_waitcnt vmcnt(8)" ::: "memory");
  BARF();
  LDS_AQ(0, 0, 0);
  LDS_BF(0, 0);

  #pragma unroll 1
  for (int g = 0; g < NG; ++g) {
    const int buf = g & 1;
    const u16* Asrc = At + ((g + 2) & 15) * 64;
    const u16* Bsrc = Bbase + (long)((g + 2) >> 4) * 262144 + ((g + 2) & 15) * 64;

    LDS_BF(buf, 2);
    LDS_AQ(1, buf, 1);
    QUAD8(0, 0, 0);
    BARF();
    QUAD8(0, 0, 2);
    BARF();
    LDS_AQ(0, buf, 2);
    if (g + 2 < NG) { STAGE(buf, 2, Bsrc); STAGE(buf, 3, Bsrc + 131072); }
    QUAD8(1, 1, 0);
    BARF();
    QUAD8(1, 1, 2);
    BARF();
    LDS_AQ(1, buf, 3);
    QUAD8(0, 2, 0);
    BARF();
    QUAD8(0, 2, 2);
    asm volatile("s_waitcnt lgkmcnt(0)" ::: "memory");
    __builtin_amdgcn_sched_barrier(0);
    BARF();
    if (g + 2 < NG) { STAGE(buf, 0, Asrc); STAGE(buf, 1, Asrc + 131072); }
    QUAD8(1, 3, 0);
    BARF();
    if (g < NG - 2)       { asm volatile("s_waitcnt vmcnt(8)" ::: "memory"); }
    else if (g == NG - 2) { asm volatile("s_waitcnt vmcnt(0)" ::: "memory"); }
    BARF();
    if (g + 1 < NG) {
      LDS_AQ(0, buf ^ 1, 0);
      LDS_BF(buf ^ 1, 0);
    }
    QUAD8(1, 3, 2);
    BARF();

    if ((g & 15) == 15) {             // panel boundary: write output, clear acc
      epilogue(g >> 4);
      if (g + 1 < NG) {
        #pragma unroll
        for (int mi = 0; mi < 8; ++mi)
          #pragma unroll
          for (int ni = 0; ni < 4; ++ni) acc[mi][ni] = f32x4{0.f, 0.f, 0.f, 0.f};
      }
    }
  }
#undef STAGE
#undef LDS_AQ
#undef LDS_BF
#undef QUAD8
#undef BARF
}

// ------------- causal flash attention: 8-wave blocks, half-seq q-range per block -------------
// R17: grid 1024 = 2 halves x 512 (b,h). half0: q 0-255 (nch=4), half1: q 256-511 (nch=8).
// Per (b,h): 12 chunk loads vs 20 with 4-wave qi-blocks (-40% K/V staging), each chunk
// shared by 8 waves. Wave-activity drops 90%->75% (causal idling) but attn is staging/
// latency-bound, not MFMA-bound. Occupancy: ~96 VGPR -> 2 blocks/CU = 16 waves (same).
// Q PRE-SCALED -> P = exp2(s). No max tracking. t.s[j] compile-time (R13 lesson).
__global__ __launch_bounds__(512, 2)
void k_attn(const u16* __restrict__ Qp, const u16* __restrict__ Kp,
            const u16* __restrict__ Vp, u16* __restrict__ ctx) {
  __shared__ u16 k_lds[2][64 * 72];   // K chunk [s][d], stride 72
  __shared__ u16 vt_lds[2][64 * 72];  // V^T chunk [d][sigma(s)], stride 72

  const int bid = blockIdx.x;
  const int half = 1 - (bid >> 9);    // LPT: heavy half (q 256-511) first
  const int bh = bid & 511;
  const int tid = threadIdx.x, lane = tid & 63, w = tid >> 6;   // 8 waves
  const int lg = lane >> 4, lr = lane & 15;
  const long base = (long)bh * (512 * 64);

  const int q0 = half * 256 + w * 32; // this wave's 32 q-rows

#define LBAR() { asm volatile("s_waitcnt lgkmcnt(0)" ::: "memory");            \
                 __builtin_amdgcn_sched_barrier(0);                            \
                 asm volatile("s_barrier" ::: "memory"); }

  bf16x8 qf[2][2];                    // B-frag of Q (pre-scaled): col q=lr, k-slot d=lg*8+j
  #pragma unroll
  for (int mt = 0; mt < 2; ++mt)
    #pragma unroll
    for (int k2 = 0; k2 < 2; ++k2)
      qf[mt][k2] = *(const bf16x8*)(Qp + base + (long)(q0 + mt * 16 + lr) * 64 + k2 * 32 + lg * 8);

  f32x4 o[2][4] = {};                 // O^T: row d = dt*16+lg*4+r, col q = mt*16+lr
  float ls[2] = {0.f, 0.f};           // lane-partial row sums
  u32 pkw[2][4][2];                   // P^T bf16 fragments of chunk c-1 (persist)

  const int nch = (half + 1) * 4;     // 64-row K/V chunks needed (causal)
  // staging: 512 threads x 1 uint4 = 64x64 chunk
  const int srow = tid >> 3, scol = tid & 7;
  const int cslot = ((srow >> 5) << 5) + (((srow >> 2) & 3) << 3) + (((srow >> 4) & 1) << 2) + (srow & 3);

  uint4 kreg, vreg;
  auto loadch = [&](int c) {
    long go = base + (long)(c * 64 + srow) * 64 + scol * 8;
    kreg = *(const uint4*)(Kp + go);
    vreg = *(const uint4*)(Vp + go);
  };
  auto writech = [&](int bsel) {
    *(uint4*)&k_lds[bsel][srow * 72 + scol * 8] = kreg;
    union { uint4 v; u16 s[8]; } t; t.v = vreg;
    #pragma unroll
    for (int j = 0; j < 8; ++j)
      vt_lds[bsel][(scol * 8 + j) * 72 + cslot] = t.s[j];
  };
  auto pv_step = [&](int vsel) {      // o += V^T(vsel) . pkw
    bf16x8 vf2[4][2];
    #pragma unroll
    for (int dt = 0; dt < 4; ++dt)
      #pragma unroll
      for (int k2 = 0; k2 < 2; ++k2)
        vf2[dt][k2] = *(const bf16x8*)&vt_lds[vsel][(dt * 16 + lr) * 72 + k2 * 32 + lg * 8];
    __builtin_amdgcn_s_setprio(1);
    #pragma unroll
    for (int k2 = 0; k2 < 2; ++k2)
      #pragma unroll
      for (int mt = 0; mt < 2; ++mt) {
        union { u32 w4[4]; bf16x8 v; } pb;
        pb.w4[0] = pkw[mt][2 * k2][0];
        pb.w4[1] = pkw[mt][2 * k2][1];
        pb.w4[2] = pkw[mt][2 * k2 + 1][0];
        pb.w4[3] = pkw[mt][2 * k2 + 1][1];
        #pragma unroll
        for (int dt = 0; dt < 4; ++dt)
          o[mt][dt] = __builtin_amdgcn_mfma_f32_16x16x32_bf16(vf2[dt][k2], pb.v, o[mt][dt], 0, 0, 0);
      }
    __builtin_amdgcn_s_setprio(0);
  };

  loadch(0);
  writech(0);
  loadch(1);
  __syncthreads();

  #pragma unroll 1
  for (int c = 0; c < nch; ++c) {
    const int bsel = c & 1;
    const bool doQK = (c * 64 <= q0 + 31);
    const bool doPV = (c >= 1) && ((c - 1) * 64 <= q0 + 31);

    bf16x8 kf2[4][2];
    if (doQK) {                       // issue K reads early; drain under PV (LDS FIFO)
      #pragma unroll
      for (int nt = 0; nt < 4; ++nt)
        #pragma unroll
        for (int k2 = 0; k2 < 2; ++k2)
          kf2[nt][k2] = *(const bf16x8*)&k_lds[bsel][(nt * 16 + lr) * 72 + k2 * 32 + lg * 8];
    }

    if (doPV) pv_step(bsel ^ 1);      // PV of chunk c-1

    f32x4 st[2][4] = {};
    if (doQK) {
      __builtin_amdgcn_s_setprio(1);
      #pragma unroll
      for (int k2 = 0; k2 < 2; ++k2)
        #pragma unroll
        for (int mt = 0; mt < 2; ++mt)
          #pragma unroll
          for (int nt = 0; nt < 4; ++nt)
            st[mt][nt] = __builtin_amdgcn_mfma_f32_16x16x32_bf16(kf2[nt][k2], qf[mt][k2], st[mt][nt], 0, 0, 0);
      __builtin_amdgcn_s_setprio(0);

      const bool full = (c * 64 + 63 <= q0);
      #pragma unroll
      for (int mt = 0; mt < 2; ++mt) {
        const int q = q0 + mt * 16 + lr;
        if (!full) {
          #pragma unroll
          for (int nt = 0; nt < 4; ++nt)
            #pragma unroll
            for (int r = 0; r < 4; ++r) {
              int s_ = c * 64 + nt * 16 + lg * 4 + r;
              st[mt][nt][r] = (s_ <= q) ? st[mt][nt][r] : -1e30f;
            }
        }
        float ps = 0.f;
        float p[4][4];
        #pragma unroll
        for (int nt = 0; nt < 4; ++nt)
          #pragma unroll
          for (int r = 0; r < 4; ++r) {
            float pv = exp2f(st[mt][nt][r]);   // Q pre-scaled; exp2(-1e30)=0 masks
            p[nt][r] = pv;
            ps += pv;
          }
        ls[mt] += ps;
        #pragma unroll
        for (int nt = 0; nt < 4; ++nt) {
          pkw[mt][nt][0] = cvtpk(p[nt][0], p[nt][1]);
          pkw[mt][nt][1] = cvtpk(p[nt][2], p[nt][3]);
        }
      }
    }

    LBAR();                           // reads of bsel^1 done (own-wave lgkm + barrier)
    if (c + 1 < nch) writech(bsel ^ 1);
    if (c + 2 < nch) loadch(c + 2);   // stays in flight across LBAR (no vmcnt drain)
    LBAR();                           // ds_writes visible for next iteration
  }

  if ((nch - 1) * 64 <= q0 + 31) pv_step((nch - 1) & 1);

  const int b = bh >> 4, h = bh & 15;
  #pragma unroll
  for (int mt = 0; mt < 2; ++mt) {
    float l = ls[mt];
    l += __shfl_xor(l, 16);
    l += __shfl_xor(l, 32);
    const float inv = 1.0f / l;
    const int t = q0 + mt * 16 + lr;
    #pragma unroll
    for (int dt = 0; dt < 4; ++dt) {
      u16x4 pk4;
      #pragma unroll
      for (int r = 0; r < 4; ++r) pk4[r] = f2bf(o[mt][dt][r] * inv);
      *(u16x4*)(ctx + ((long)(b * 512 + t)) * 1024 + h * 64 + dt * 16 + lg * 4) = pk4;
    }
  }
#undef LBAR
}

extern "C" void kernel_launch(void* const* d_in, const int* in_sizes, int n_in,
                              void* d_out, int out_size, void* d_ws, size_t ws_size,
                              hipStream_t stream) {
  const float* x  = (const float*)d_in[0];
  const float* wq = (const float*)d_in[1];
  const float* wk = (const float*)d_in[2];
  const float* wv = (const float*)d_in[3];
  const float* wp = (const float*)d_in[4];
  const float* bp = (const float*)d_in[5];
  float* out = (float*)d_out;
  u16* ws = (u16*)d_ws;

  u16* XB    = ws + XB_O;
  u16* WQKV  = ws + WQKV_O;
  u16* Qb    = ws + Q_O;
  u16* CTX   = ws + CTX_O;
  u16* WPROJ = ws + WPROJ_O;

  k_prep_all<<<9216, 256, 0, stream>>>(x, wq, wk, wv, wp, ws);
  k_gemm<3072, 0, 3><<<256, 512, 0, stream>>>(XB, WQKV, Qb, nullptr, nullptr);
  k_attn<<<1024, 512, 0, stream>>>(Qb, Qb + QS_, Qb + 2 * QS_, CTX);
  k_gemm<1024, 1, 1><<<256, 512, 0, stream>>>(CTX, WPROJ, nullptr, out, bp);
}

// Round 18
// 218.120 us; speedup vs baseline: 1.0645x; 1.0645x over previous
//
#include <hip/hip_runtime.h>

typedef unsigned int u32;
typedef unsigned short u16;
typedef __bf16 bf16x8 __attribute__((ext_vector_type(8)));
typedef float f32x4 __attribute__((ext_vector_type(4)));
typedef u16 u16x8 __attribute__((ext_vector_type(8)));
typedef u16 u16x4 __attribute__((ext_vector_type(4)));

#define DEVI static __device__ __forceinline__

DEVI u16 f2bf(float f) {
  union { float f; u32 u; } v; v.f = f;
  return (u16)((v.u + 0x7fffu + ((v.u >> 16) & 1u)) >> 16);
}

DEVI u32 cvtpk(float a, float b) {  // lo=bf16(a), hi=bf16(b)
  u32 r;
  asm("v_cvt_pk_bf16_f32 %0, %1, %2" : "=v"(r) : "v"(a), "v"(b));
  return r;
}

// Problem constants: B=32, T=512, C=1024, H=16, D=64
constexpr long QS_ = 16777216;            // B*H*T*D elements (one of Q/K/V)
constexpr long XB_O    = 0;               // [16384][1024] bf16 x
constexpr long WQKV_O  = 16777216;        // [3072][1024]  bf16 fused W^T (q|k|v)
constexpr long Q_O     = 19922944;        // Q,K,V each [B*H][T][D] bf16 (Q pre-scaled!)
constexpr long CTX_O   = 70254592;        // [16384][1024] bf16 attention output
constexpr long WPROJ_O = 87031808;        // [1024][1024]  bf16 w_proj^T

// (1/sqrt(C)) * log2(e): folded into Q at GEMM1 epilogue so attn does exp2(s) directly.
#define SCL_Q 0.045084220027780106f

// ------------- fused prep: 64x64 LDS-transpose W packs (coalesced both sides) + x cast -------------
__global__ __launch_bounds__(256) void k_prep_all(const float* __restrict__ x,
                                                  const float* __restrict__ wq,
                                                  const float* __restrict__ wk,
                                                  const float* __restrict__ wv,
                                                  const float* __restrict__ wp,
                                                  u16* __restrict__ ws) {
  __shared__ float tile[64][65];
  const int b = blockIdx.x;
  const int tid = threadIdx.x;
  if (b < 1024) {
    const float* src;
    u16* dst;
    long srs;
    if (b < 768) {
      int sel = b >> 8, rest = b & 255, h = rest >> 4, kt = rest & 15;
      const float* W = (sel == 0) ? wq : ((sel == 1) ? wk : wv);
      src = W + (long)(h * 1024 + kt * 64) * 64;
      srs = 64;
      dst = ws + WQKV_O + (long)(sel * 1024 + h * 64) * 1024 + kt * 64;
    } else {
      int b3 = b - 768, ntile = b3 >> 4, kt = b3 & 15;
      src = wp + (long)(kt * 64) * 1024 + ntile * 64;
      srs = 1024;
      dst = ws + WPROJ_O + (long)(ntile * 64) * 1024 + kt * 64;
    }
    #pragma unroll
    for (int i = 0; i < 4; ++i) {
      int idx = i * 256 + tid, r = idx >> 4, c4 = idx & 15;
      float4 v = *(const float4*)(src + (long)r * srs + c4 * 4);
      tile[r][c4 * 4 + 0] = v.x; tile[r][c4 * 4 + 1] = v.y;
      tile[r][c4 * 4 + 2] = v.z; tile[r][c4 * 4 + 3] = v.w;
    }
    __syncthreads();
    #pragma unroll
    for (int i = 0; i < 2; ++i) {
      int idx = i * 256 + tid, dr = idx >> 3, c8 = idx & 7;
      u16x8 o8;
      #pragma unroll
      for (int j = 0; j < 8; ++j) o8[j] = f2bf(tile[c8 * 8 + j][dr]);
      *(u16x8*)(dst + (long)dr * 1024 + c8 * 8) = o8;
    }
  } else {
    long id = (long)(b - 1024) * 256 + tid;
    const float4* p = (const float4*)(x + id * 8);
    float4 a = p[0], c = p[1];
    u16x8 r;
    r[0]=f2bf(a.x); r[1]=f2bf(a.y); r[2]=f2bf(a.z); r[3]=f2bf(a.w);
    r[4]=f2bf(c.x); r[5]=f2bf(c.y); r[6]=f2bf(c.z); r[7]=f2bf(c.w);
    *(u16x8*)(ws + XB_O + id * 8) = r;
  }
}

DEVI void gload16(const u16* g, u16* l) {
  __builtin_amdgcn_global_load_lds((const __attribute__((address_space(1))) u32*)g,
                                   (__attribute__((address_space(3))) u32*)l, 16, 0, 0);
}

// ===================== 256x256 bf16 GEMM, 8 micro-phases, persistent PANELS =====================
// FROZEN (R15 state). Structural closure: acc(128 reg-equiv) + frags => ~236 regs/wave =>
// 1 block/CU hard bound; 128-tile @3 blocks/CU measured worse (R2: 763 TF vs 885 here).
template <int NN, int EPI, int PANELS>
__global__ __launch_bounds__(512, 2)
void k_gemm(const u16* __restrict__ A, const u16* __restrict__ Bt,
            u16* __restrict__ oq, float* __restrict__ of, const float* __restrict__ bias) {
  __shared__ u16 lds[2][4][8192];   // [buf][Alo,Ahi,Blo,Bhi]

  const int tid = threadIdx.x;
  const int lane = tid & 63;
  const int w = tid >> 6;           // 8 waves
  const int wm = w >> 2, wn = w & 3;
  const int lg = lane >> 4, lr = lane & 15;
  const int bht = 2 + (wn >> 1);    // this wave's B half-tile
  const int bn0 = (wn & 1) * 4;     // B subtile-row base within half-tile

  constexpr int NBG = NN / 256 / PANELS;   // bn groups per bm
  constexpr int NG = 16 * PANELS;          // total K-tiles across panels
  const int nwg = gridDim.x;
  const int swz = ((int)blockIdx.x & 7) * (nwg >> 3) + ((int)blockIdx.x >> 3);
  const int bm = swz / NBG, bng = swz % NBG;
  const long m0 = (long)bm * 256;

  int srcoff[2];
  #pragma unroll
  for (int r2 = 0; r2 < 2; ++r2) {
    int s = r2 * 8 + w;
    int mi = s >> 1, ks = s & 1;
    int rowl = mi * 16 + (lane >> 2);
    int colu = ks * 32 + (((lane & 3) * 8) ^ (((lane >> 5) & 1) * 16));
    srcoff[r2] = rowl * 1024 + colu;
  }
  const int fo = lr * 32 + ((lg * 8) ^ (((lr >> 3) & 1) * 16));

  const u16* At    = A  + m0 * 1024;
  const u16* Bbase = Bt + (long)bng * PANELS * 262144;   // 256 rows * 1024 per panel

  f32x4 acc[8][4] = {};
  bf16x8 aq[2][2][2];   // [set][mi2][ks] ping-pong A quarters
  bf16x8 bfr[4][2];     // persistent B fragments (all 4 nj)

#define STAGE(buf_, ht_, gbase_)                                               \
  { _Pragma("unroll") for (int r_ = 0; r_ < 2; ++r_)                           \
      gload16((gbase_) + srcoff[r_], &lds[buf_][ht_][r_ * 4096 + w * 512]); }

#define LDS_AQ(set_, buf_, q_)                                                 \
  { _Pragma("unroll") for (int i_ = 0; i_ < 2; ++i_)                           \
    _Pragma("unroll") for (int ks_ = 0; ks_ < 2; ++ks_)                        \
      aq[set_][i_][ks_] = *(const bf16x8*)&lds[buf_][wm][(((q_)*2 + i_) * 2 + ks_) * 512 + fo]; }

#define LDS_BF(buf_, lo_)                                                      \
  { _Pragma("unroll") for (int j_ = 0; j_ < 2; ++j_)                           \
    _Pragma("unroll") for (int ks_ = 0; ks_ < 2; ++ks_)                        \
      bfr[(lo_) + j_][ks_] = *(const bf16x8*)&lds[buf_][bht][((bn0 + (lo_) + j_) * 2 + ks_) * 512 + fo]; }

#define QUAD8(set_, q_, lo_)                                                   \
  { __builtin_amdgcn_s_setprio(1);                                             \
    _Pragma("unroll") for (int ks_ = 0; ks_ < 2; ++ks_)                        \
    _Pragma("unroll") for (int i_ = 0; i_ < 2; ++i_)                           \
    _Pragma("unroll") for (int j_ = 0; j_ < 2; ++j_)                           \
      acc[(q_)*2 + i_][(lo_) + j_] = __builtin_amdgcn_mfma_f32_16x16x32_bf16(  \
          aq[set_][i_][ks_], bfr[(lo_) + j_][ks_], acc[(q_)*2 + i_][(lo_) + j_], 0, 0, 0); \
    __builtin_amdgcn_s_setprio(0); }

#define BARF() { asm volatile("s_barrier" ::: "memory"); }

  auto epilogue = [&](int p) {
    const int n0 = (bng * PANELS + p) * 256;
    if constexpr (EPI == 0) {
      #pragma unroll
      for (int mi = 0; mi < 8; ++mi) {
        int grow = (int)m0 + wm * 128 + mi * 16 + lg * 4;
        int b = grow >> 9, t0 = grow & 511;
        #pragma unroll
        for (int ni = 0; ni < 4; ++ni) {
          int gcol = n0 + wn * 64 + ni * 16 + lr;
          int sel = gcol >> 10, h = (gcol >> 6) & 15, d = gcol & 63;
          float scl = (sel == 0) ? SCL_Q : 1.0f;   // fold softmax scale into Q
          u16* dst = oq + (long)sel * QS_ + (((long)(b * 16 + h) * 512 + t0) * 64 + d);
          #pragma unroll
          for (int r = 0; r < 4; ++r) dst[r * 64] = f2bf(acc[mi][ni][r] * scl);
        }
      }
    } else {
      float bv[4];
      #pragma unroll
      for (int ni = 0; ni < 4; ++ni) bv[ni] = bias[n0 + wn * 64 + ni * 16 + lr];
      #pragma unroll
      for (int mi = 0; mi < 8; ++mi) {
        int grow = (int)m0 + wm * 128 + mi * 16 + lg * 4;
        #pragma unroll
        for (int ni = 0; ni < 4; ++ni) {
          int gcol = n0 + wn * 64 + ni * 16 + lr;
          #pragma unroll
          for (int r = 0; r < 4; ++r)
            of[(long)(grow + r) * NN + gcol] = acc[mi][ni][r] + bv[ni];
        }
      }
    }
  };

  STAGE(0, 0, At);
  STAGE(0, 1, At + 131072);
  STAGE(0, 2, Bbase);
  STAGE(0, 3, Bbase + 131072);
  STAGE(1, 0, At + 64);
  STAGE(1, 1, At + 131072 + 64);
  STAGE(1, 2, Bbase + 64);
  STAGE(1, 3, Bbase + 131072 + 64);
  asm volatile("s_waitcnt vmcnt(8)" ::: "memory");
  BARF();
  LDS_AQ(0, 0, 0);
  LDS_BF(0, 0);

  #pragma unroll 1
  for (int g = 0; g < NG; ++g) {
    const int buf = g & 1;
    const u16* Asrc = At + ((g + 2) & 15) * 64;
    const u16* Bsrc = Bbase + (long)((g + 2) >> 4) * 262144 + ((g + 2) & 15) * 64;

    LDS_BF(buf, 2);
    LDS_AQ(1, buf, 1);
    QUAD8(0, 0, 0);
    BARF();
    QUAD8(0, 0, 2);
    BARF();
    LDS_AQ(0, buf, 2);
    if (g + 2 < NG) { STAGE(buf, 2, Bsrc); STAGE(buf, 3, Bsrc + 131072); }
    QUAD8(1, 1, 0);
    BARF();
    QUAD8(1, 1, 2);
    BARF();
    LDS_AQ(1, buf, 3);
    QUAD8(0, 2, 0);
    BARF();
    QUAD8(0, 2, 2);
    asm volatile("s_waitcnt lgkmcnt(0)" ::: "memory");
    __builtin_amdgcn_sched_barrier(0);
    BARF();
    if (g + 2 < NG) { STAGE(buf, 0, Asrc); STAGE(buf, 1, Asrc + 131072); }
    QUAD8(1, 3, 0);
    BARF();
    if (g < NG - 2)       { asm volatile("s_waitcnt vmcnt(8)" ::: "memory"); }
    else if (g == NG - 2) { asm volatile("s_waitcnt vmcnt(0)" ::: "memory"); }
    BARF();
    if (g + 1 < NG) {
      LDS_AQ(0, buf ^ 1, 0);
      LDS_BF(buf ^ 1, 0);
    }
    QUAD8(1, 3, 2);
    BARF();

    if ((g & 15) == 15) {             // panel boundary: write output, clear acc
      epilogue(g >> 4);
      if (g + 1 < NG) {
        #pragma unroll
        for (int mi = 0; mi < 8; ++mi)
          #pragma unroll
          for (int ni = 0; ni < 4; ++ni) acc[mi][ni] = f32x4{0.f, 0.f, 0.f, 0.f};
      }
    }
  }
#undef STAGE
#undef LDS_AQ
#undef LDS_BF
#undef QUAD8
#undef BARF
}

// ------------- causal flash attention, swapped (S^T/O^T), 1-chunk-lag PV pipeline -------------
// R15-measured-best config (218.1 us total). 4-wave blocks, qi-LPT, kf2 hoisted before
// pv_step (LDS FIFO drains them under PV MFMA). Q PRE-SCALED -> P = exp2(s), no max
// tracking (|s| <~ 2 fp32-safe; softmax shift-invariant). l lane-partial, reduced at end.
// (256,3): known-good ~96 VGPR; (256,4) -> VGPR=64 spill disaster (R9). t.s[j] MUST be
// compile-time indexed (R13 scratch lesson). 8-wave merge regressed (R17: +12 us, causal
// idle dominates). Raw-barrier LBAR variant neutral (R16).
__global__ __launch_bounds__(256, 3)
void k_attn(const u16* __restrict__ Qp, const u16* __restrict__ Kp,
            const u16* __restrict__ Vp, u16* __restrict__ ctx) {
  __shared__ u16 k_lds[2][64 * 72];   // K chunk [s][d], stride 72
  __shared__ u16 vt_lds[2][64 * 72];  // V^T chunk [d][sigma(s)], stride 72

  const int bid = blockIdx.x;
  const int qi = 3 - (bid >> 9);      // LPT: heaviest q-tiles dispatched first
  const int bh = bid & 511;
  const int tid = threadIdx.x, lane = tid & 63, w = tid >> 6;
  const int lg = lane >> 4, lr = lane & 15;
  const long base = (long)bh * (512 * 64);

  const int q0 = qi * 128 + w * 32;   // this wave's 32 q-rows

  bf16x8 qf[2][2];                    // B-frag of Q (pre-scaled): col q=lr, k-slot d=lg*8+j
  #pragma unroll
  for (int mt = 0; mt < 2; ++mt)
    #pragma unroll
    for (int k2 = 0; k2 < 2; ++k2)
      qf[mt][k2] = *(const bf16x8*)(Qp + base + (long)(q0 + mt * 16 + lr) * 64 + k2 * 32 + lg * 8);

  f32x4 o[2][4] = {};                 // O^T: row d = dt*16+lg*4+r, col q = mt*16+lr
  float ls[2] = {0.f, 0.f};           // lane-partial row sums
  u32 pkw[2][4][2];                   // P^T bf16 fragments of chunk c-1 (persist)

  const int nch = (qi + 1) * 2;       // 64-row K/V chunks (causal)
  int srow[2], scol[2], cslot[2];
  #pragma unroll
  for (int i = 0; i < 2; ++i) {
    int s = i * 256 + tid;
    srow[i] = s >> 3; scol[i] = s & 7;
    int sr = srow[i];                 // sigma: slot = k2*32 + b*8 + a*4 + c
    cslot[i] = ((sr >> 5) << 5) + (((sr >> 2) & 3) << 3) + (((sr >> 4) & 1) << 2) + (sr & 3);
  }

  uint4 kreg[2], vreg[2];
  auto loadch = [&](int c) {
    #pragma unroll
    for (int i = 0; i < 2; ++i) {
      long go = base + (long)(c * 64 + srow[i]) * 64 + scol[i] * 8;
      kreg[i] = *(const uint4*)(Kp + go);
      vreg[i] = *(const uint4*)(Vp + go);
    }
  };
  auto writech = [&](int bsel) {
    #pragma unroll
    for (int i = 0; i < 2; ++i) {
      *(uint4*)&k_lds[bsel][srow[i] * 72 + scol[i] * 8] = kreg[i];
      union { uint4 v; u16 s[8]; } t; t.v = vreg[i];
      #pragma unroll
      for (int j = 0; j < 8; ++j)
        vt_lds[bsel][(scol[i] * 8 + j) * 72 + cslot[i]] = t.s[j];
    }
  };
  auto pv_step = [&](int vsel) {      // o += V^T(vsel) . pkw
    bf16x8 vf2[4][2];
    #pragma unroll
    for (int dt = 0; dt < 4; ++dt)
      #pragma unroll
      for (int k2 = 0; k2 < 2; ++k2)
        vf2[dt][k2] = *(const bf16x8*)&vt_lds[vsel][(dt * 16 + lr) * 72 + k2 * 32 + lg * 8];
    __builtin_amdgcn_s_setprio(1);
    #pragma unroll
    for (int k2 = 0; k2 < 2; ++k2)
      #pragma unroll
      for (int mt = 0; mt < 2; ++mt) {
        union { u32 w4[4]; bf16x8 v; } pb;
        pb.w4[0] = pkw[mt][2 * k2][0];
        pb.w4[1] = pkw[mt][2 * k2][1];
        pb.w4[2] = pkw[mt][2 * k2 + 1][0];
        pb.w4[3] = pkw[mt][2 * k2 + 1][1];
        #pragma unroll
        for (int dt = 0; dt < 4; ++dt)
          o[mt][dt] = __builtin_amdgcn_mfma_f32_16x16x32_bf16(vf2[dt][k2], pb.v, o[mt][dt], 0, 0, 0);
      }
    __builtin_amdgcn_s_setprio(0);
  };

  loadch(0);
  writech(0);
  loadch(1);
  __syncthreads();

  #pragma unroll 1
  for (int c = 0; c < nch; ++c) {
    const int bsel = c & 1;
    const bool doQK = (c * 64 <= q0 + 31);
    const bool doPV = (c >= 1) && ((c - 1) * 64 <= q0 + 31);

    bf16x8 kf2[4][2];
    if (doQK) {                       // issue K reads early; drain under PV (LDS FIFO)
      #pragma unroll
      for (int nt = 0; nt < 4; ++nt)
        #pragma unroll
        for (int k2 = 0; k2 < 2; ++k2)
          kf2[nt][k2] = *(const bf16x8*)&k_lds[bsel][(nt * 16 + lr) * 72 + k2 * 32 + lg * 8];
    }

    if (doPV) pv_step(bsel ^ 1);      // PV of chunk c-1

    f32x4 st[2][4] = {};
    if (doQK) {
      __builtin_amdgcn_s_setprio(1);
      #pragma unroll
      for (int k2 = 0; k2 < 2; ++k2)
        #pragma unroll
        for (int mt = 0; mt < 2; ++mt)
          #pragma unroll
          for (int nt = 0; nt < 4; ++nt)
            st[mt][nt] = __builtin_amdgcn_mfma_f32_16x16x32_bf16(kf2[nt][k2], qf[mt][k2], st[mt][nt], 0, 0, 0);
      __builtin_amdgcn_s_setprio(0);

      const bool full = (c * 64 + 63 <= q0);
      #pragma unroll
      for (int mt = 0; mt < 2; ++mt) {
        const int q = q0 + mt * 16 + lr;
        if (!full) {
          #pragma unroll
          for (int nt = 0; nt < 4; ++nt)
            #pragma unroll
            for (int r = 0; r < 4; ++r) {
              int s_ = c * 64 + nt * 16 + lg * 4 + r;
              st[mt][nt][r] = (s_ <= q) ? st[mt][nt][r] : -1e30f;
            }
        }
        float ps = 0.f;
        float p[4][4];
        #pragma unroll
        for (int nt = 0; nt < 4; ++nt)
          #pragma unroll
          for (int r = 0; r < 4; ++r) {
            float pv = exp2f(st[mt][nt][r]);   // Q pre-scaled; exp2(-1e30)=0 masks
            p[nt][r] = pv;
            ps += pv;
          }
        ls[mt] += ps;
        #pragma unroll
        for (int nt = 0; nt < 4; ++nt) {
          pkw[mt][nt][0] = cvtpk(p[nt][0], p[nt][1]);
          pkw[mt][nt][1] = cvtpk(p[nt][2], p[nt][3]);
        }
      }
    }

    __syncthreads();
    if (c + 1 < nch) writech(bsel ^ 1);
    if (c + 2 < nch) loadch(c + 2);
    __syncthreads();
  }

  if ((nch - 1) * 64 <= q0 + 31) pv_step((nch - 1) & 1);

  const int b = bh >> 4, h = bh & 15;
  #pragma unroll
  for (int mt = 0; mt < 2; ++mt) {
    float l = ls[mt];
    l += __shfl_xor(l, 16);
    l += __shfl_xor(l, 32);
    const float inv = 1.0f / l;
    const int t = q0 + mt * 16 + lr;
    #pragma unroll
    for (int dt = 0; dt < 4; ++dt) {
      u16x4 pk4;
      #pragma unroll
      for (int r = 0; r < 4; ++r) pk4[r] = f2bf(o[mt][dt][r] * inv);
      *(u16x4*)(ctx + ((long)(b * 512 + t)) * 1024 + h * 64 + dt * 16 + lg * 4) = pk4;
    }
  }
}

extern "C" void kernel_launch(void* const* d_in, const int* in_sizes, int n_in,
                              void* d_out, int out_size, void* d_ws, size_t ws_size,
                              hipStream_t stream) {
  const float* x  = (const float*)d_in[0];
  const float* wq = (const float*)d_in[1];
  const float* wk = (const float*)d_in[2];
  const float* wv = (const float*)d_in[3];
  const float* wp = (const float*)d_in[4];
  const float* bp = (const float*)d_in[5];
  float* out = (float*)d_out;
  u16* ws = (u16*)d_ws;

  u16* XB    = ws + XB_O;
  u16* WQKV  = ws + WQKV_O;
  u16* Qb    = ws + Q_O;
  u16* CTX   = ws + CTX_O;
  u16* WPROJ = ws + WPROJ_O;

  k_prep_all<<<9216, 256, 0, stream>>>(x, wq, wk, wv, wp, ws);
  k_gemm<3072, 0, 3><<<256, 512, 0, stream>>>(XB, WQKV, Qb, nullptr, nullptr);
  k_attn<<<2048, 256, 0, stream>>>(Qb, Qb + QS_, Qb + 2 * QS_, CTX);
  k_gemm<1024, 1, 1><<<256, 512, 0, stream>>>(CTX, WPROJ, nullptr, out, bp);
}